// Round 7
// baseline (2801.229 us; speedup 1.0000x reference)
//
#include <hip/hip_runtime.h>
#include <stdint.h>

// Problem dims
#define HDIM   1024
#define BDIM   128
#define TSTEPS 128
#define DDIM   256
#define ODIM   1024

// Workspace byte offsets (stamps: 256 blocks x 64B line, monotonic 2t+half+1)
#define WS_STAMP 0
#define WS_HBUF  16384                                 // ushort [2][128][1024]
#define WS_HFIN  (WS_HBUF + 2*BDIM*HDIM*2)             // (unused, layout kept)
#define WS_PBUF  (WS_HFIN + BDIM*HDIM*4)               // float  [128][1024]
#define WS_WHHI  (WS_PBUF + BDIM*ODIM*4)               // ushort [4096][1024]
#define WS_WHLO  (WS_WHHI + 4*HDIM*HDIM*2)             // ushort [4096][1024]
#define WS_WXHI  (WS_WHLO + 4*HDIM*HDIM*2)             // ushort [4096][256]
#define WS_XT    (WS_WXHI + 4*HDIM*DDIM*2)             // ushort [128][128][256]

// LDS (main loop): weights in FRAG-LINEAR order -> ds_read_b128 fully sequential
// per wave (conflict-free), ONE shared copy per block (not 4 register copies).
#define SW_HI   0                      // [32 kc][64 lane][16B] = 32768 B
#define SW_LO   32768                  // 32768 B
#define SW_X    65536                  // [8 kc][64 lane][16B] = 8192 B
#define SG_OFF  73728                  // [64][17] f32 = 4352 B -> ends 78080
// Epilogue reuses smem as sH [64][1032] u16 = 132096 B + sRed.
#define SMEM_H_ROW 1032
#define SMEM_BYTES (64*SMEM_H_ROW*2 + 256)   // 132,352 B -> 1 block/CU

typedef __attribute__((ext_vector_type(8))) short frag8;
typedef __attribute__((ext_vector_type(4))) float f32x4;

__device__ __forceinline__ unsigned short f2bf(float f) {
  union { float f; unsigned u; } v; v.f = f;
  unsigned r = v.u + 0x7fffu + ((v.u >> 16) & 1u);   // RNE
  return (unsigned short)(r >> 16);
}
__device__ __forceinline__ float bf2f(unsigned short h) {
  union { unsigned u; float f; } v; v.u = ((unsigned)h) << 16;
  return v.f;
}
__device__ __forceinline__ float sigm(float x) { return 1.f / (1.f + __expf(-x)); }
__device__ __forceinline__ float tanh_f(float x) {
  x = fminf(fmaxf(x, -20.f), 20.f);
  float e = __expf(2.f * x);
  return (e - 1.f) / (e + 1.f);
}

// Fence-free coherence (gfx950, validated R5): producers use relaxed AGENT atomic
// stores (write-through, L2 never dirty); __syncthreads drains vmcnt(0) before the
// tid0 stamp publish; consumers use relaxed AGENT atomic loads (sc1 -> LLC-fresh).
__device__ __forceinline__ void st_agent_u32(unsigned* p, unsigned v) {
  __hip_atomic_store(p, v, __ATOMIC_RELAXED, __HIP_MEMORY_SCOPE_AGENT);
}
__device__ __forceinline__ void st_agent_u64(unsigned long long* p, unsigned long long v) {
  __hip_atomic_store(p, v, __ATOMIC_RELAXED, __HIP_MEMORY_SCOPE_AGENT);
}
__device__ __forceinline__ void st_agent_f32(float* p, float v) {
  __hip_atomic_store(p, v, __ATOMIC_RELAXED, __HIP_MEMORY_SCOPE_AGENT);
}
__device__ __forceinline__ unsigned long long ld_agent_u64(const unsigned long long* p) {
  return __hip_atomic_load(p, __ATOMIC_RELAXED, __HIP_MEMORY_SCOPE_AGENT);
}
__device__ __forceinline__ unsigned ld_agent_u32(const unsigned* p) {
  return __hip_atomic_load(p, __ATOMIC_RELAXED, __HIP_MEMORY_SCOPE_AGENT);
}

// ---------------- prep: fp32 -> bf16 (hi/lo) reformat + x transpose ----------------
__global__ void prep_kernel(const float* __restrict__ Wh, const float* __restrict__ Wx,
                            const float* __restrict__ x, unsigned char* __restrict__ ws)
{
  unsigned short* whhi = (unsigned short*)(ws + WS_WHHI);
  unsigned short* whlo = (unsigned short*)(ws + WS_WHLO);
  unsigned short* wxhi = (unsigned short*)(ws + WS_WXHI);
  unsigned short* xt   = (unsigned short*)(ws + WS_XT);
  const int NWH = 4*HDIM*HDIM/4;       // 1,048,576 float4 items
  const int NWX = 4*HDIM*DDIM/4;       //   262,144
  const int NX  = BDIM*TSTEPS*DDIM/4;  // 1,048,576
  int stride = gridDim.x * blockDim.x;
  for (int i = blockIdx.x*blockDim.x + threadIdx.x; i < NWH+NWX+NX; i += stride) {
    if (i < NWH) {
      float4 w = ((const float4*)Wh)[i];
      ushort4 hi, lo;
      hi.x = f2bf(w.x); lo.x = f2bf(w.x - bf2f(hi.x));
      hi.y = f2bf(w.y); lo.y = f2bf(w.y - bf2f(hi.y));
      hi.z = f2bf(w.z); lo.z = f2bf(w.z - bf2f(hi.z));
      hi.w = f2bf(w.w); lo.w = f2bf(w.w - bf2f(hi.w));
      ((ushort4*)whhi)[i] = hi;
      ((ushort4*)whlo)[i] = lo;
    } else if (i < NWH + NWX) {
      int j = i - NWH;
      float4 w = ((const float4*)Wx)[j];
      ushort4 hi;
      hi.x = f2bf(w.x); hi.y = f2bf(w.y); hi.z = f2bf(w.z); hi.w = f2bf(w.w);
      ((ushort4*)wxhi)[j] = hi;
    } else {
      int j = i - NWH - NWX;           // x flat [b][t][dv], dv = float4 index
      int dv = j & 63;
      int t  = (j >> 6) & (TSTEPS - 1);
      int b  = j >> 13;
      float4 w = ((const float4*)x)[j];
      ushort4 hv;
      hv.x = f2bf(w.x); hv.y = f2bf(w.y); hv.z = f2bf(w.z); hv.w = f2bf(w.w);
      ((ushort4*)xt)[((size_t)t*BDIM + b)*64 + dv] = hv;   // xT[t][b][d]
    }
  }
}

// ---------------- persistent LSTM kernel (cooperative, 256 blocks x 256 thr) ----------------
// Partition (R6 structure): block n owns h-cols [4n, 4n+4) (16 gate rows, N=16) for
// ALL 128 batch rows. The two batch halves are independent recurrences; the block
// alternates half-0/half-1 so each chain's barrier+LLC latencies hide under the
// other chain's compute. Weights: LDS frag-linear (shared, conflict-free b128).
// Single monotonic stamp/block: value 2t+half+1 after publishing h(half, t+1).
__global__ void __launch_bounds__(256, 1)
lstm_main(const float* __restrict__ bx, const float* __restrict__ Wp,
          const float* __restrict__ bp, unsigned char* __restrict__ ws,
          float* __restrict__ out)
{
  extern __shared__ unsigned char smem[];
  float* sG = (float*)(smem + SG_OFF);           // [64][17] fp32 (main loop)

  unsigned*       stamp = (unsigned*)(ws + WS_STAMP);    // [256] x 16 dwords
  unsigned short* hbuf  = (unsigned short*)(ws + WS_HBUF);
  float*          pbuf  = (float*)(ws + WS_PBUF);
  const unsigned short* whhi = (const unsigned short*)(ws + WS_WHHI);
  const unsigned short* whlo = (const unsigned short*)(ws + WS_WHLO);
  const unsigned short* wxhi = (const unsigned short*)(ws + WS_WXHI);
  const unsigned short* xt   = (const unsigned short*)(ws + WS_XT);

  const int tid  = threadIdx.x;
  const int lane = tid & 63;
  const int wv   = tid >> 6;      // wave 0..3 -> m-tile within the half
  const int fr   = lane & 15;     // MFMA frag row (m for A, n for B)
  const int fg   = lane >> 4;     // k-group 0..3
  const int hc0  = blockIdx.x * 4;   // this block's 4 h-columns

  // ---- prologue: stage this block's 16 gate rows into LDS, FRAG-LINEAR order ----
  // frag(lane l, kc) at byte (kc*64+l)*16; value = W[grow(l&15)][kc*32 + (l>>4)*8 + j]
  {
    const int l = lane;
    const int kcg = wv;                       // wave w stages kc in [8w, 8w+8)
    int grow = (fr >> 2)*HDIM + hc0 + (fr & 3);
    const unsigned long long* ph = (const unsigned long long*)(whhi + (size_t)grow*HDIM + fg*8);
    const unsigned long long* pl = (const unsigned long long*)(whlo + (size_t)grow*HDIM + fg*8);
    const unsigned long long* px = (const unsigned long long*)(wxhi + (size_t)grow*DDIM + fg*8);
    unsigned long long* dh = (unsigned long long*)(smem + SW_HI);
    unsigned long long* dl = (unsigned long long*)(smem + SW_LO);
    unsigned long long* dx = (unsigned long long*)(smem + SW_X);
    #pragma unroll
    for (int k2 = 0; k2 < 8; ++k2) {
      int kc = kcg*8 + k2;
      dh[(kc*64 + l)*2]     = ph[kc*8];
      dh[(kc*64 + l)*2 + 1] = ph[kc*8 + 1];
      dl[(kc*64 + l)*2]     = pl[kc*8];
      dl[(kc*64 + l)*2 + 1] = pl[kc*8 + 1];
    }
    #pragma unroll
    for (int k2 = 0; k2 < 2; ++k2) {
      int kc = kcg*2 + k2;
      dx[(kc*64 + l)*2]     = px[kc*8];
      dx[(kc*64 + l)*2 + 1] = px[kc*8 + 1];
    }
  }
  __syncthreads();

  // gate biases for this block's 16 gate rows (j = gate*4 + col); used by tid<64
  float bxv[16];
  #pragma unroll
  for (int j = 0; j < 16; ++j)
    bxv[j] = bx[(j >> 2)*HDIM + hc0 + (j & 3)];

  float cst0[4] = {0.f,0.f,0.f,0.f};   // c-state, half 0 (thread<64: its row)
  float cst1[4] = {0.f,0.f,0.f,0.f};   // c-state, half 1

  const unsigned* sp = stamp + (unsigned)tid * 16;   // thread tid polls block tid

  const unsigned short* swh = (const unsigned short*)(smem + SW_HI);
  const unsigned short* swl = (const unsigned short*)(smem + SW_LO);
  const unsigned short* swx = (const unsigned short*)(smem + SW_X);

  for (int t = 0; t < TSTEPS; ++t) {
    #pragma unroll
    for (int half = 0; half < 2; ++half) {
      // ---- wait: all blocks published h(half, t) ----
      int target = 2*t + half - 1;
      if (target >= 1) {
        while (ld_agent_u32(sp) < (unsigned)target)
          __builtin_amdgcn_s_sleep(1);
        __syncthreads();
      }

      const int arow = half*64 + wv*16 + fr;
      f32x4 ah = {0.f,0.f,0.f,0.f}, al = {0.f,0.f,0.f,0.f}, ax = {0.f,0.f,0.f,0.f};

      // x-path (cached loads; xt read-only; B from LDS frag-linear)
      {
        const unsigned long long* xa =
            (const unsigned long long*)(xt + ((size_t)t*BDIM + arow)*DDIM + fg*8);
        #pragma unroll
        for (int kc = 0; kc < 8; ++kc) {
          union { unsigned long long q[2]; frag8 f; } a;
          a.q[0] = xa[kc*8]; a.q[1] = xa[kc*8 + 1];
          frag8 b = *(const frag8*)(swx + (kc*64 + lane)*8);
          ax = __builtin_amdgcn_mfma_f32_16x16x32_bf16(a.f, b, ax, 0, 0, 0);
        }
      }

      // h-path (sc1 atomic loads, LLC-fresh; B from LDS frag-linear, conflict-free)
      {
        const unsigned long long* ha =
            (const unsigned long long*)(hbuf + ((size_t)(t & 1)*BDIM + arow)*HDIM + fg*8);
        #pragma unroll 8
        for (int kc = 0; kc < 32; ++kc) {
          union { unsigned long long q[2]; frag8 f; } a;
          a.q[0] = ld_agent_u64(ha + kc*8);
          a.q[1] = ld_agent_u64(ha + kc*8 + 1);
          frag8 bh = *(const frag8*)(swh + (kc*64 + lane)*8);
          frag8 bl = *(const frag8*)(swl + (kc*64 + lane)*8);
          ah = __builtin_amdgcn_mfma_f32_16x16x32_bf16(a.f, bh, ah, 0, 0, 0);
          al = __builtin_amdgcn_mfma_f32_16x16x32_bf16(a.f, bl, al, 0, 0, 0);
        }
      }

      f32x4 acc = ah + al + ax;

      // scatter to sG[64][17] (C/D layout: col=lane&15, row=(lane>>4)*4+reg)
      {
        int mb = wv*16 + fg*4;
        #pragma unroll
        for (int r = 0; r < 4; ++r)
          sG[(mb + r)*17 + fr] = acc[r];
      }
      __syncthreads();

      // gate phase: wave 0 only; thread = one batch row of this half, all 4 cols
      if (tid < 64) {
        float* cst = half ? cst1 : cst0;
        const float* gr = sG + tid*17;
        float v[16];
        #pragma unroll
        for (int j = 0; j < 16; ++j) v[j] = gr[j] + bxv[j];
        float hs[4];
        #pragma unroll
        for (int c = 0; c < 4; ++c) {
          float cc = tanh_f(v[c])*sigm(v[4 + c]) + cst[c]*sigm(v[8 + c]);
          cst[c] = cc;
          hs[c] = tanh_f(cc)*sigm(v[12 + c]);
        }
        unsigned lo32 = (unsigned)f2bf(hs[0]) | ((unsigned)f2bf(hs[1]) << 16);
        unsigned hi32 = (unsigned)f2bf(hs[2]) | ((unsigned)f2bf(hs[3]) << 16);
        unsigned long long hv = (unsigned long long)lo32 | ((unsigned long long)hi32 << 32);
        unsigned long long* hw = (unsigned long long*)
            (hbuf + ((size_t)((t + 1) & 1)*BDIM + half*64 + tid)*HDIM + hc0);
        st_agent_u64(hw, hv);
      }
      __syncthreads();   // drains vmcnt(0) (h at LLC) before barrier release

      if (tid == 0)
        st_agent_u32(stamp + (unsigned)blockIdx.x*16, (unsigned)(2*t + half + 1));
    }
  }

  // ---- wait: all chains done (stamp = 2*TSTEPS); final h in hbuf slot 0 ----
  {
    while (ld_agent_u32(sp) < (unsigned)(2*TSTEPS))
      __builtin_amdgcn_s_sleep(1);
  }
  __syncthreads();

  // ---- epilogue partition (as R5): mh = blockIdx&1 rows, 8 out-cols ----
  const int mh  = blockIdx.x & 1;
  const int m0e = mh << 6;
  const int hc0e = (blockIdx.x >> 1) << 3;

  // stage h_T rows [m0e, m0e+64) into LDS: 16384 u64, 256 u64/row
  {
    unsigned short* sH = (unsigned short*)smem;      // [64][1032]
    const unsigned long long* hsrc = (const unsigned long long*)(hbuf + (size_t)m0e*HDIM);
    #pragma unroll 4
    for (int i = 0; i < 64; ++i) {
      int q = i*256 + tid;
      int row = q >> 8, off = q & 255;
      unsigned long long v = ld_agent_u64(hsrc + q);
      ((unsigned long long*)(sH + row*SMEM_H_ROW))[off] = v;
    }
  }
  __syncthreads();

  // projection: p = h_T @ Wp^T + bp (bf16 h from LDS, fp32 accumulate)
  {
    const unsigned short* sH = (const unsigned short*)smem;
    #pragma unroll
    for (int it = 0; it < 2; ++it) {
      int ml = (tid >> 3) + it*32;
      int n  = hc0e + (tid & 7);
      const unsigned short* hr = sH + ml*SMEM_H_ROW;
      const float4* wr = (const float4*)(Wp + (size_t)n*HDIM);
      float s = 0.f;
      #pragma unroll 4
      for (int k = 0; k < 128; ++k) {
        const ushort4* hp = (const ushort4*)(hr + k*8);
        ushort4 ha = hp[0], hb = hp[1];
        float4 wa = wr[2*k], wb = wr[2*k + 1];
        s += bf2f(ha.x)*wa.x + bf2f(ha.y)*wa.y + bf2f(ha.z)*wa.z + bf2f(ha.w)*wa.w;
        s += bf2f(hb.x)*wb.x + bf2f(hb.y)*wb.y + bf2f(hb.z)*wb.z + bf2f(hb.w)*wb.w;
      }
      st_agent_f32(&pbuf[(size_t)(m0e + ml)*ODIM + n], s + bp[n]);
    }
  }
  __syncthreads();
  if (tid == 0)
    st_agent_u32(stamp + (unsigned)blockIdx.x*16, (unsigned)(2*TSTEPS + 1));

  if (blockIdx.x >= BDIM) return;

  // wait: all 256 blocks' projections done
  {
    while (ld_agent_u32(sp) < (unsigned)(2*TSTEPS + 1))
      __builtin_amdgcn_s_sleep(1);
  }
  __syncthreads();

  // softmax: one block per batch row (pbuf via sc1 u64 loads)
  {
    float* sRed = (float*)(smem + 64*SMEM_H_ROW*2);
    int b = blockIdx.x;
    const unsigned long long* pr = (const unsigned long long*)(pbuf + (size_t)b*ODIM);
    union { unsigned long long q; float f[2]; } u0, u1;
    u0.q = ld_agent_u64(pr + 2*tid);
    u1.q = ld_agent_u64(pr + 2*tid + 1);
    float4 v; v.x = u0.f[0]; v.y = u0.f[1]; v.z = u1.f[0]; v.w = u1.f[1];
    float mx = fmaxf(fmaxf(v.x, v.y), fmaxf(v.z, v.w));
    #pragma unroll
    for (int off = 32; off > 0; off >>= 1)
      mx = fmaxf(mx, __shfl_xor(mx, off, 64));
    if (lane == 0) sRed[wv] = mx;
    __syncthreads();
    mx = fmaxf(fmaxf(sRed[0], sRed[1]), fmaxf(sRed[2], sRed[3]));
    float e0 = __expf(v.x - mx), e1 = __expf(v.y - mx),
          e2 = __expf(v.z - mx), e3 = __expf(v.w - mx);
    float s = e0 + e1 + e2 + e3;
    #pragma unroll
    for (int off = 32; off > 0; off >>= 1)
      s += __shfl_xor(s, off, 64);
    if (lane == 0) sRed[8 + wv] = s;
    __syncthreads();
    s = sRed[8] + sRed[9] + sRed[10] + sRed[11];
    float inv = 1.f / s;
    float4 o; o.x = e0*inv; o.y = e1*inv; o.z = e2*inv; o.w = e3*inv;
    ((float4*)(out + (size_t)b*ODIM))[tid] = o;
  }
}

// ---------------- host launch ----------------
extern "C" void kernel_launch(void* const* d_in, const int* in_sizes, int n_in,
                              void* d_out, int out_size, void* d_ws, size_t ws_size,
                              hipStream_t stream) {
  (void)in_sizes; (void)n_in; (void)out_size; (void)ws_size;
  const float* x  = (const float*)d_in[0];
  const float* Wx = (const float*)d_in[1];
  const float* bx = (const float*)d_in[2];
  const float* Wh = (const float*)d_in[3];
  const float* Wp = (const float*)d_in[4];
  const float* bp = (const float*)d_in[5];
  float* out = (float*)d_out;
  unsigned char* ws = (unsigned char*)d_ws;

  // zero stamps + h0 double-buffer slot 0
  hipMemsetAsync(ws, 0, WS_HBUF + BDIM*HDIM*2, stream);

  hipLaunchKernelGGL(prep_kernel, dim3(1024), dim3(256), 0, stream, Wh, Wx, x, ws);

  hipFuncSetAttribute(reinterpret_cast<const void*>(&lstm_main),
                      hipFuncAttributeMaxDynamicSharedMemorySize, SMEM_BYTES);
  void* args[5];
  args[0] = (void*)&bx; args[1] = (void*)&Wp; args[2] = (void*)&bp;
  args[3] = (void*)&ws; args[4] = (void*)&out;
  hipLaunchCooperativeKernel(reinterpret_cast<const void*>(&lstm_main),
                             dim3(256), dim3(256), args, SMEM_BYTES, stream);
}